// Round 2
// baseline (1623.490 us; speedup 1.0000x reference)
//
#include <hip/hip_runtime.h>
#include <hip/hip_fp16.h>
#include <hip/hip_cooperative_groups.h>

namespace cg = cooperative_groups;

#define BB 4096
#define NN 4096
#define RPB 2        // rows per block in k_K
#define SGRID 512    // cooperative grid: 2 blocks/CU * 256 CUs (validation headroom)
#define RPS (BB / SGRID)   // 8 rows per block per sinkhorn phase

// ---------------- mean(D) reduction + v=1 init ----------------
__global__ __launch_bounds__(256) void k_mean(
        const float* __restrict__ Dt, float* __restrict__ dsum,
        float* __restrict__ v) {
    const int tid = blockIdx.x * blockDim.x + threadIdx.x;
    if (tid < NN) v[tid] = 1.0f;
    const float4* D4 = (const float4*)Dt;
    const int total4 = (BB * NN) / 4;
    float s = 0.f;
    for (int i = tid; i < total4; i += gridDim.x * blockDim.x) {
        float4 d = D4[i];
        s += (d.x + d.y) + (d.z + d.w);
    }
    #pragma unroll
    for (int off = 32; off > 0; off >>= 1) s += __shfl_down(s, off, 64);
    __shared__ float ls[4];
    if ((threadIdx.x & 63) == 0) ls[threadIdx.x >> 6] = s;
    __syncthreads();
    if (threadIdx.x == 0) atomicAdd(dsum, (ls[0] + ls[1]) + (ls[2] + ls[3]));
}

// ---------------- K = exp(5*dot - 5*D/mean), fp16, fp16 lut ----------------
__global__ __launch_bounds__(256) void k_K(
        const int* __restrict__ users, const int* __restrict__ pois,
        const float* __restrict__ Dt, const float* __restrict__ poi_emb,
        const float* __restrict__ user_emb, const float* __restrict__ dsum,
        __half* __restrict__ K) {
    __shared__ __half slut[RPB][NN];      // 16 KB -> 8 blocks/CU
    __shared__ float ues[RPB * 16];
    const int t = threadIdx.x;
    const int b0 = blockIdx.x * RPB;
    if (t < RPB * 16) {
        int r = t >> 4, d = t & 15;
        ues[t] = user_emb[(size_t)users[b0 + r] * 16 + d];
    }
    __syncthreads();
    float ue[RPB][16];
    #pragma unroll
    for (int r = 0; r < RPB; r++)
        #pragma unroll
        for (int d = 0; d < 16; d++) ue[r][d] = ues[r * 16 + d];

    const float4* pe4 = (const float4*)poi_emb;
    for (int j = t; j < NN; j += 256) {
        float4 p0 = pe4[j * 4 + 0];
        float4 p1 = pe4[j * 4 + 1];
        float4 p2 = pe4[j * 4 + 2];
        float4 p3 = pe4[j * 4 + 3];
        #pragma unroll
        for (int r = 0; r < RPB; r++) {
            float acc = p0.x*ue[r][0]  + p0.y*ue[r][1]  + p0.z*ue[r][2]  + p0.w*ue[r][3]
                      + p1.x*ue[r][4]  + p1.y*ue[r][5]  + p1.z*ue[r][6]  + p1.w*ue[r][7]
                      + p2.x*ue[r][8]  + p2.y*ue[r][9]  + p2.z*ue[r][10] + p2.w*ue[r][11]
                      + p3.x*ue[r][12] + p3.y*ue[r][13] + p3.z*ue[r][14] + p3.w*ue[r][15];
            slut[r][j] = __float2half(acc);
        }
    }
    __syncthreads();                       // lut read-only from here on
    const float cc = 5.0f * 16777216.0f / dsum[0];   // 5 / mean(D)
    #pragma unroll
    for (int r = 0; r < RPB; r++) {
        const size_t base = (size_t)(b0 + r) * NN;
        const int4*   p4 = (const int4*)(pois + base);
        const float4* d4 = (const float4*)(Dt + base);
        #pragma unroll
        for (int i = 0; i < NN / 4 / 256; i++) {     // 4
            const int q = t + i * 256;
            int4   ci = p4[q];
            float4 cd = d4[q];
            float k0 = __expf(5.0f * __half2float(slut[r][ci.x]) - cc * cd.x);
            float k1 = __expf(5.0f * __half2float(slut[r][ci.y]) - cc * cd.y);
            float k2 = __expf(5.0f * __half2float(slut[r][ci.z]) - cc * cd.z);
            float k3 = __expf(5.0f * __half2float(slut[r][ci.w]) - cc * cd.w);
            __half2* kw = (__half2*)&K[base + 4 * (size_t)q];
            kw[0] = __floats2half2_rn(k0, k1);
            kw[1] = __floats2half2_rn(k2, k3);
        }
    }
}

// ---------------- fp16 row-chunk dot helper ----------------
__device__ __forceinline__ float dot16h(float4 h0, float4 h1,
        float4 wa0, float4 wa1, float4 wb0, float4 wb1) {
    const __half2* a = (const __half2*)&h0;
    const __half2* b = (const __half2*)&h1;
    float s = 0.f; float2 f;
    f = __half22float2(a[0]); s += f.x * wa0.x + f.y * wa0.y;
    f = __half22float2(a[1]); s += f.x * wa0.z + f.y * wa0.w;
    f = __half22float2(a[2]); s += f.x * wa1.x + f.y * wa1.y;
    f = __half22float2(a[3]); s += f.x * wa1.z + f.y * wa1.w;
    f = __half22float2(b[0]); s += f.x * wb0.x + f.y * wb0.y;
    f = __half22float2(b[1]); s += f.x * wb0.z + f.y * wb0.w;
    f = __half22float2(b[2]); s += f.x * wb1.x + f.y * wb1.y;
    f = __half22float2(b[3]); s += f.x * wb1.z + f.y * wb1.w;
    return s;
}

// ---------------- split-kernel fallback path (round-0 proven) ----------------
__device__ __forceinline__ float rowdot(const __half* __restrict__ row,
                                        const float* __restrict__ w, int t) {
    const float4* r4 = (const float4*)row;
    float4 h0 = r4[t], h1 = r4[256 + t];
    const float4* w4 = (const float4*)w;
    float4 wa0 = w4[2 * t], wa1 = w4[2 * t + 1];
    float4 wb0 = w4[512 + 2 * t], wb1 = w4[512 + 2 * t + 1];
    float s = dot16h(h0, h1, wa0, wa1, wb0, wb1);
    #pragma unroll
    for (int off = 32; off > 0; off >>= 1) s += __shfl_down(s, off, 64);
    __shared__ float ls[4];
    if ((t & 63) == 0) ls[t >> 6] = s;
    __syncthreads();
    return (ls[0] + ls[1]) + (ls[2] + ls[3]);
}

__global__ __launch_bounds__(256) void k_T(
        const __half* __restrict__ K, __half* __restrict__ KT) {
    __shared__ __half tile[64][72];       // +8 pad
    const int t = threadIdx.x;
    const int r = t >> 2;                 // 0..63
    const int q = t & 3;                  // 0..3
    const int n0 = blockIdx.x * 64;
    const int b0 = blockIdx.y * 64;
    #pragma unroll
    for (int i = 0; i < 2; i++) {
        int cseg = (q + 4 * i) * 8;
        float4 f = *(const float4*)&K[(size_t)(b0 + r) * NN + n0 + cseg];
        *(float4*)&tile[r][cseg] = f;
    }
    __syncthreads();
    #pragma unroll
    for (int i = 0; i < 2; i++) {
        int cseg = (q + 4 * i) * 8;
        __half tmp[8];
        #pragma unroll
        for (int k = 0; k < 8; k++) tmp[k] = tile[cseg + k][r];
        *(float4*)&KT[(size_t)(n0 + r) * BB + b0 + cseg] = *(float4*)tmp;
    }
}

__global__ __launch_bounds__(256) void k_u(
        const __half* __restrict__ K, const float* __restrict__ v,
        float* __restrict__ u) {
    float s = rowdot(K + (size_t)blockIdx.x * NN, v, threadIdx.x);
    if (threadIdx.x == 0) u[blockIdx.x] = 1.0f / s;
}

__global__ __launch_bounds__(256) void k_v(
        const __half* __restrict__ KT, const float* __restrict__ u,
        const float* __restrict__ cap, float* __restrict__ v) {
    float s = rowdot(KT + (size_t)blockIdx.x * BB, u, threadIdx.x);
    if (threadIdx.x == 0) v[blockIdx.x] = cap[blockIdx.x] / s;
}

__global__ __launch_bounds__(256) void k_P_h(
        const __half* __restrict__ K, const float* __restrict__ u,
        const float* __restrict__ v, float* __restrict__ P) {
    const int i = blockIdx.x * 256 + threadIdx.x;  // half8 index
    const int e = i * 8;
    const int b = e >> 12;
    const int col = e & 4095;
    float4 raw = ((const float4*)K)[i];
    const __half2* h = (const __half2*)&raw;
    const float ub = u[b];
    float4 v0 = ((const float4*)v)[col >> 2];
    float4 v1 = ((const float4*)v)[(col >> 2) + 1];
    float2 f0 = __half22float2(h[0]);
    float2 f1 = __half22float2(h[1]);
    float2 f2 = __half22float2(h[2]);
    float2 f3 = __half22float2(h[3]);
    ((float4*)P)[e >> 2]       = make_float4(f0.x*ub*v0.x, f0.y*ub*v0.y,
                                             f1.x*ub*v0.z, f1.y*ub*v0.w);
    ((float4*)P)[(e >> 2) + 1] = make_float4(f2.x*ub*v1.x, f2.y*ub*v1.y,
                                             f3.x*ub*v1.z, f3.y*ub*v1.w);
}

// ---------------- cooperative: transpose + 10 sinkhorn iters + P ----------------
// 8 block-wide row dots: rows r0..r0+7 of M (fp16, ld=4096) against w (fp32).
// Returns dot for row r0+t, valid only on t<8.
__device__ __forceinline__ float block_dots8(
        const __half* M, int r0, const float* w, int t, float (*ls)[8]) {
    const float4* w4 = (const float4*)w;
    float4 wa0 = w4[2 * t], wa1 = w4[2 * t + 1];
    float4 wb0 = w4[512 + 2 * t], wb1 = w4[512 + 2 * t + 1];
    float acc[8];
    #pragma unroll
    for (int r = 0; r < 8; r++) {
        const float4* r4 = (const float4*)(M + (size_t)(r0 + r) * NN);
        float4 h0 = r4[t], h1 = r4[256 + t];
        acc[r] = dot16h(h0, h1, wa0, wa1, wb0, wb1);
    }
    #pragma unroll
    for (int off = 32; off > 0; off >>= 1) {
        #pragma unroll
        for (int r = 0; r < 8; r++) acc[r] += __shfl_down(acc[r], off, 64);
    }
    __syncthreads();                      // ls may still be read from prior call
    if ((t & 63) == 0) {
        #pragma unroll
        for (int r = 0; r < 8; r++) ls[t >> 6][r] = acc[r];
    }
    __syncthreads();
    float s = 0.f;
    if (t < 8) s = (ls[0][t] + ls[1][t]) + (ls[2][t] + ls[3][t]);
    return s;
}

// NOTE: KT and P alias (both live in d_out) -> deliberately NOT __restrict__.
__global__ __launch_bounds__(256, 4) void k_sink(
        const __half* __restrict__ Kh, __half* KT,
        float* __restrict__ u, float* __restrict__ v,
        const float* __restrict__ cap, float* P) {
    __shared__ __half tile[64][72];       // 9216 B
    __shared__ float ls[4][8];
    cg::grid_group gg = cg::this_grid();
    const int t = threadIdx.x;
    const int bid = blockIdx.x;
    const int r0 = bid * RPS;             // 8 rows per block per phase

    // ---- phase T: transpose Kh -> KT, 8 64x64 tiles per block ----
    {
        const int tr = t >> 2, tq = t & 3;
        #pragma unroll 1
        for (int tt = 0; tt < RPS; tt++) {
            const int tid8 = bid * RPS + tt;       // 0..4095
            const int n0 = (tid8 & 63) << 6;
            const int b0 = (tid8 >> 6) << 6;
            #pragma unroll
            for (int i = 0; i < 2; i++) {
                const int cseg = (tq + 4 * i) * 8;
                *(float4*)&tile[tr][cseg] =
                    *(const float4*)&Kh[(size_t)(b0 + tr) * NN + n0 + cseg];
            }
            __syncthreads();
            #pragma unroll
            for (int i = 0; i < 2; i++) {
                const int cseg = (tq + 4 * i) * 8;
                __half tmp[8];
                #pragma unroll
                for (int k = 0; k < 8; k++) tmp[k] = tile[cseg + k][tr];
                *(float4*)&KT[(size_t)(n0 + tr) * BB + b0 + cseg] = *(float4*)tmp;
            }
            __syncthreads();
        }
    }
    gg.sync();

    // ---- 10 sinkhorn iterations ----
    #pragma unroll 1
    for (int it = 0; it < 10; it++) {
        float su = block_dots8(Kh, r0, v, t, ls);      // u = 1/(K v)
        if (t < 8) u[r0 + t] = 1.0f / su;
        gg.sync();
        float sv = block_dots8(KT, r0, u, t, ls);      // v = cap/(KT u)
        if (t < 8) v[r0 + t] = cap[r0 + t] / sv;
        gg.sync();
    }

    // ---- phase P: P = K * u[b] * v[n], 8 rows per block ----
    {
        const float4* v4 = (const float4*)v;
        float4 v0 = v4[4 * t], v1 = v4[4 * t + 1];
        float4 v2 = v4[4 * t + 2], v3 = v4[4 * t + 3];
        #pragma unroll 1
        for (int r = 0; r < RPS; r++) {
            const int b = r0 + r;
            const float ub = u[b];
            const size_t base = (size_t)b * NN;
            const float4* k4 = (const float4*)(Kh + base);
            float4 raw0 = k4[2 * t], raw1 = k4[2 * t + 1];
            const __half2* h0 = (const __half2*)&raw0;
            const __half2* h1 = (const __half2*)&raw1;
            float2 fa = __half22float2(h0[0]);
            float2 fb = __half22float2(h0[1]);
            float2 fc = __half22float2(h0[2]);
            float2 fd = __half22float2(h0[3]);
            float2 fe = __half22float2(h1[0]);
            float2 ff = __half22float2(h1[1]);
            float2 fg = __half22float2(h1[2]);
            float2 fh = __half22float2(h1[3]);
            float4* P4 = (float4*)(P + base);
            P4[4 * t + 0] = make_float4(fa.x*ub*v0.x, fa.y*ub*v0.y, fb.x*ub*v0.z, fb.y*ub*v0.w);
            P4[4 * t + 1] = make_float4(fc.x*ub*v1.x, fc.y*ub*v1.y, fd.x*ub*v1.z, fd.y*ub*v1.w);
            P4[4 * t + 2] = make_float4(fe.x*ub*v2.x, fe.y*ub*v2.y, ff.x*ub*v2.z, ff.y*ub*v2.w);
            P4[4 * t + 3] = make_float4(fg.x*ub*v3.x, fg.y*ub*v3.y, fh.x*ub*v3.z, fh.y*ub*v3.w);
        }
    }
}

extern "C" void kernel_launch(void* const* d_in, const int* in_sizes, int n_in,
                              void* d_out, int out_size, void* d_ws, size_t ws_size,
                              hipStream_t stream) {
    const int*   users    = (const int*)d_in[0];
    const int*   pois     = (const int*)d_in[1];
    const float* Dt       = (const float*)d_in[2];
    const float* poi_emb  = (const float*)d_in[3];
    const float* user_emb = (const float*)d_in[4];
    const float* cap      = (const float*)d_in[5];
    float* out = (float*)d_out;

    float*  wsf  = (float*)d_ws;
    float*  dsum = wsf;                        // [1]
    float*  u    = wsf + 64;                   // [BB]
    float*  v    = wsf + 64 + BB;              // [NN]
    __half* Kh   = (__half*)(wsf + 64 + BB + NN);   // [BB*NN] fp16 = 33.5 MB
    __half* KT   = (__half*)d_out;             // first 33.5 MB of out; dead before P phase

    hipMemsetAsync(dsum, 0, sizeof(float), stream);
    k_mean<<<2048, 256, 0, stream>>>(Dt, dsum, v);
    k_K<<<BB / RPB, 256, 0, stream>>>(users, pois, Dt, poi_emb, user_emb, dsum, Kh);

    const __half* Kh_c = Kh;
    __half* KT_p = KT;
    float* u_p = u;
    float* v_p = v;
    const float* cap_c = cap;
    float* out_p = out;
    void* args[] = { &Kh_c, &KT_p, &u_p, &v_p, &cap_c, &out_p };
    hipError_t cerr = hipLaunchCooperativeKernel(
        reinterpret_cast<const void*>(&k_sink),
        dim3(SGRID), dim3(256), args, 0, stream);
    if (cerr != hipSuccess) {
        // fallback: proven split-kernel path (round-0 behavior)
        k_T<<<dim3(NN / 64, BB / 64), 256, 0, stream>>>(Kh, KT);
        for (int it = 0; it < 10; it++) {
            k_u<<<BB, 256, 0, stream>>>(Kh, v, u);
            k_v<<<NN, 256, 0, stream>>>(KT, u, cap, v);
        }
        k_P_h<<<(BB * NN / 8) / 256, 256, 0, stream>>>(Kh, u, v, out);
    }
}

// Round 3
// 396.561 us; speedup vs baseline: 4.0939x; 4.0939x over previous
//
#include <hip/hip_runtime.h>
#include <hip/hip_fp16.h>

#define BB 4096
#define NN 4096
#define RPB 2        // rows per block in k_K
#define RPD 4        // rows per block in k_u/k_v

// ---------------- mean(D) reduction + v=1 init ----------------
__global__ __launch_bounds__(256) void k_mean(
        const float* __restrict__ Dt, float* __restrict__ dsum,
        float* __restrict__ v) {
    const int tid = blockIdx.x * blockDim.x + threadIdx.x;
    if (tid < NN) v[tid] = 1.0f;
    const float4* D4 = (const float4*)Dt;
    const int total4 = (BB * NN) / 4;
    float s = 0.f;
    for (int i = tid; i < total4; i += gridDim.x * blockDim.x) {
        float4 d = D4[i];
        s += (d.x + d.y) + (d.z + d.w);
    }
    #pragma unroll
    for (int off = 32; off > 0; off >>= 1) s += __shfl_down(s, off, 64);
    __shared__ float ls[4];
    if ((threadIdx.x & 63) == 0) ls[threadIdx.x >> 6] = s;
    __syncthreads();
    if (threadIdx.x == 0) atomicAdd(dsum, (ls[0] + ls[1]) + (ls[2] + ls[3]));
}

// ---------------- K = exp(5*dot - 5*D/mean), fp16, fp16 lut ----------------
__global__ __launch_bounds__(256) void k_K(
        const int* __restrict__ users, const int* __restrict__ pois,
        const float* __restrict__ Dt, const float* __restrict__ poi_emb,
        const float* __restrict__ user_emb, const float* __restrict__ dsum,
        __half* __restrict__ K) {
    __shared__ __half slut[RPB][NN];      // 16 KB
    __shared__ float ues[RPB * 16];
    const int t = threadIdx.x;
    const int b0 = blockIdx.x * RPB;
    if (t < RPB * 16) {
        int r = t >> 4, d = t & 15;
        ues[t] = user_emb[(size_t)users[b0 + r] * 16 + d];
    }
    __syncthreads();
    float ue[RPB][16];
    #pragma unroll
    for (int r = 0; r < RPB; r++)
        #pragma unroll
        for (int d = 0; d < 16; d++) ue[r][d] = ues[r * 16 + d];

    const float4* pe4 = (const float4*)poi_emb;
    for (int j = t; j < NN; j += 256) {
        float4 p0 = pe4[j * 4 + 0];
        float4 p1 = pe4[j * 4 + 1];
        float4 p2 = pe4[j * 4 + 2];
        float4 p3 = pe4[j * 4 + 3];
        #pragma unroll
        for (int r = 0; r < RPB; r++) {
            float acc = p0.x*ue[r][0]  + p0.y*ue[r][1]  + p0.z*ue[r][2]  + p0.w*ue[r][3]
                      + p1.x*ue[r][4]  + p1.y*ue[r][5]  + p1.z*ue[r][6]  + p1.w*ue[r][7]
                      + p2.x*ue[r][8]  + p2.y*ue[r][9]  + p2.z*ue[r][10] + p2.w*ue[r][11]
                      + p3.x*ue[r][12] + p3.y*ue[r][13] + p3.z*ue[r][14] + p3.w*ue[r][15];
            slut[r][j] = __float2half(acc);
        }
    }
    __syncthreads();                       // lut read-only from here on
    const float cc = 5.0f * 16777216.0f / dsum[0];   // 5 / mean(D)
    #pragma unroll
    for (int r = 0; r < RPB; r++) {
        const size_t base = (size_t)(b0 + r) * NN;
        const int4*   p4 = (const int4*)(pois + base);
        const float4* d4 = (const float4*)(Dt + base);
        #pragma unroll
        for (int i = 0; i < NN / 4 / 256; i++) {     // 4
            const int q = t + i * 256;
            int4   ci = p4[q];
            float4 cd = d4[q];
            float k0 = __expf(5.0f * __half2float(slut[r][ci.x]) - cc * cd.x);
            float k1 = __expf(5.0f * __half2float(slut[r][ci.y]) - cc * cd.y);
            float k2 = __expf(5.0f * __half2float(slut[r][ci.z]) - cc * cd.z);
            float k3 = __expf(5.0f * __half2float(slut[r][ci.w]) - cc * cd.w);
            __half2* kw = (__half2*)&K[base + 4 * (size_t)q];
            kw[0] = __floats2half2_rn(k0, k1);
            kw[1] = __floats2half2_rn(k2, k3);
        }
    }
}

// ---------------- transpose Kh -> KT (64x64 fp16 tiles) ----------------
__global__ __launch_bounds__(256) void k_T(
        const __half* __restrict__ K, __half* __restrict__ KT) {
    __shared__ __half tile[64][72];       // +8 pad
    const int t = threadIdx.x;
    const int r = t >> 2;                 // 0..63
    const int q = t & 3;                  // 0..3
    const int n0 = blockIdx.x * 64;
    const int b0 = blockIdx.y * 64;
    #pragma unroll
    for (int i = 0; i < 2; i++) {
        int cseg = (q + 4 * i) * 8;
        float4 f = *(const float4*)&K[(size_t)(b0 + r) * NN + n0 + cseg];
        *(float4*)&tile[r][cseg] = f;
    }
    __syncthreads();
    #pragma unroll
    for (int i = 0; i < 2; i++) {
        int cseg = (q + 4 * i) * 8;
        __half tmp[8];
        #pragma unroll
        for (int k = 0; k < 8; k++) tmp[k] = tile[cseg + k][r];
        *(float4*)&KT[(size_t)(n0 + r) * BB + b0 + cseg] = *(float4*)tmp;
    }
}

// ---------------- fp16 16-elem dot helper ----------------
__device__ __forceinline__ float dot16h(float4 h0, float4 h1,
        float4 wa0, float4 wa1, float4 wb0, float4 wb1) {
    const __half2* a = (const __half2*)&h0;
    const __half2* b = (const __half2*)&h1;
    float s = 0.f; float2 f;
    f = __half22float2(a[0]); s += f.x * wa0.x + f.y * wa0.y;
    f = __half22float2(a[1]); s += f.x * wa0.z + f.y * wa0.w;
    f = __half22float2(a[2]); s += f.x * wa1.x + f.y * wa1.y;
    f = __half22float2(a[3]); s += f.x * wa1.z + f.y * wa1.w;
    f = __half22float2(b[0]); s += f.x * wb0.x + f.y * wb0.y;
    f = __half22float2(b[1]); s += f.x * wb0.z + f.y * wb0.w;
    f = __half22float2(b[2]); s += f.x * wb1.x + f.y * wb1.y;
    f = __half22float2(b[3]); s += f.x * wb1.z + f.y * wb1.w;
    return s;
}

// ---------------- u[b] = 1/(K[b,:].v), 4 rows per block ----------------
__global__ __launch_bounds__(256) void k_u(
        const __half* __restrict__ K, const float* __restrict__ v,
        float* __restrict__ u) {
    const int t = threadIdx.x;
    const int r0 = blockIdx.x * RPD;
    const float4* w4 = (const float4*)v;
    float4 wa0 = w4[2 * t], wa1 = w4[2 * t + 1];
    float4 wb0 = w4[512 + 2 * t], wb1 = w4[512 + 2 * t + 1];
    float4 h0[RPD], h1[RPD];
    #pragma unroll
    for (int r = 0; r < RPD; r++) {       // all 8 loads issued before any use
        const float4* r4 = (const float4*)(K + (size_t)(r0 + r) * NN);
        h0[r] = r4[t];
        h1[r] = r4[256 + t];
    }
    float acc[RPD];
    #pragma unroll
    for (int r = 0; r < RPD; r++) acc[r] = dot16h(h0[r], h1[r], wa0, wa1, wb0, wb1);
    #pragma unroll
    for (int off = 32; off > 0; off >>= 1)
        #pragma unroll
        for (int r = 0; r < RPD; r++) acc[r] += __shfl_down(acc[r], off, 64);
    __shared__ float ls[4][RPD];
    if ((t & 63) == 0)
        #pragma unroll
        for (int r = 0; r < RPD; r++) ls[t >> 6][r] = acc[r];
    __syncthreads();
    if (t < RPD)
        u[r0 + t] = 1.0f / ((ls[0][t] + ls[1][t]) + (ls[2][t] + ls[3][t]));
}

// ---------------- v[n] = cap[n]/(KT[n,:].u), 4 rows per block ----------------
__global__ __launch_bounds__(256) void k_v(
        const __half* __restrict__ KT, const float* __restrict__ u,
        const float* __restrict__ cap, float* __restrict__ v) {
    const int t = threadIdx.x;
    const int r0 = blockIdx.x * RPD;
    const float4* w4 = (const float4*)u;
    float4 wa0 = w4[2 * t], wa1 = w4[2 * t + 1];
    float4 wb0 = w4[512 + 2 * t], wb1 = w4[512 + 2 * t + 1];
    float4 h0[RPD], h1[RPD];
    #pragma unroll
    for (int r = 0; r < RPD; r++) {
        const float4* r4 = (const float4*)(KT + (size_t)(r0 + r) * BB);
        h0[r] = r4[t];
        h1[r] = r4[256 + t];
    }
    float acc[RPD];
    #pragma unroll
    for (int r = 0; r < RPD; r++) acc[r] = dot16h(h0[r], h1[r], wa0, wa1, wb0, wb1);
    #pragma unroll
    for (int off = 32; off > 0; off >>= 1)
        #pragma unroll
        for (int r = 0; r < RPD; r++) acc[r] += __shfl_down(acc[r], off, 64);
    __shared__ float ls[4][RPD];
    if ((t & 63) == 0)
        #pragma unroll
        for (int r = 0; r < RPD; r++) ls[t >> 6][r] = acc[r];
    __syncthreads();
    if (t < RPD)
        v[r0 + t] = cap[r0 + t] / ((ls[0][t] + ls[1][t]) + (ls[2][t] + ls[3][t]));
}

// ---------------- P = K * u[b] * v[n], grid-stride ----------------
__global__ __launch_bounds__(256) void k_P_h(
        const __half* __restrict__ K, const float* __restrict__ u,
        const float* __restrict__ v, float* __restrict__ P) {
    const int stride = gridDim.x * 256;
    for (int i = blockIdx.x * 256 + threadIdx.x; i < BB * NN / 8; i += stride) {
        const int e = i * 8;
        const int b = e >> 12;
        const int col = e & 4095;
        float4 raw = ((const float4*)K)[i];
        const __half2* h = (const __half2*)&raw;
        const float ub = u[b];
        float4 v0 = ((const float4*)v)[col >> 2];
        float4 v1 = ((const float4*)v)[(col >> 2) + 1];
        float2 f0 = __half22float2(h[0]);
        float2 f1 = __half22float2(h[1]);
        float2 f2 = __half22float2(h[2]);
        float2 f3 = __half22float2(h[3]);
        ((float4*)P)[e >> 2]       = make_float4(f0.x*ub*v0.x, f0.y*ub*v0.y,
                                                 f1.x*ub*v0.z, f1.y*ub*v0.w);
        ((float4*)P)[(e >> 2) + 1] = make_float4(f2.x*ub*v1.x, f2.y*ub*v1.y,
                                                 f3.x*ub*v1.z, f3.y*ub*v1.w);
    }
}

extern "C" void kernel_launch(void* const* d_in, const int* in_sizes, int n_in,
                              void* d_out, int out_size, void* d_ws, size_t ws_size,
                              hipStream_t stream) {
    const int*   users    = (const int*)d_in[0];
    const int*   pois     = (const int*)d_in[1];
    const float* Dt       = (const float*)d_in[2];
    const float* poi_emb  = (const float*)d_in[3];
    const float* user_emb = (const float*)d_in[4];
    const float* cap      = (const float*)d_in[5];
    float* out = (float*)d_out;

    float*  wsf  = (float*)d_ws;
    float*  dsum = wsf;                        // [1]
    float*  u    = wsf + 64;                   // [BB]
    float*  v    = wsf + 64 + BB;              // [NN]
    __half* Kh   = (__half*)(wsf + 64 + BB + NN);   // [BB*NN] fp16 = 33.5 MB
    __half* KT   = (__half*)d_out;             // first 33.5 MB of out; dead before k_P

    hipMemsetAsync(dsum, 0, sizeof(float), stream);
    k_mean<<<2048, 256, 0, stream>>>(Dt, dsum, v);
    k_K<<<BB / RPB, 256, 0, stream>>>(users, pois, Dt, poi_emb, user_emb, dsum, Kh);
    k_T<<<dim3(NN / 64, BB / 64), 256, 0, stream>>>(Kh, KT);
    for (int it = 0; it < 10; it++) {
        k_u<<<BB / RPD, 256, 0, stream>>>(Kh, v, u);
        k_v<<<NN / RPD, 256, 0, stream>>>(KT, u, cap, v);
    }
    k_P_h<<<2048, 256, 0, stream>>>(Kh, u, v, out);
}